// Round 6
// baseline (191.445 us; speedup 1.0000x reference)
//
#include <hip/hip_runtime.h>
#include <math.h>

// N_AGENTS=16, RNN_H=64, N_HEADS=4, GAT_D=32, EMB=32, SDIM=128, B=4096 rows

typedef __attribute__((ext_vector_type(8))) short short8;
typedef __attribute__((ext_vector_type(8))) unsigned short ushort8;
typedef __attribute__((ext_vector_type(4))) unsigned short ushort4v;
typedef __attribute__((ext_vector_type(4))) float float4v;
typedef __attribute__((ext_vector_type(4))) _Float16 half4v;

static __device__ inline unsigned short f2bf(float f) {
    unsigned int x;
    __builtin_memcpy(&x, &f, 4);
    unsigned int r = x + 0x7fffu + ((x >> 16) & 1u);   // RNE
    return (unsigned short)(r >> 16);
}

static __device__ inline short8 pack8(float4 f0, float4 f1) {
    ushort8 o;
    o[0] = f2bf(f0.x); o[1] = f2bf(f0.y); o[2] = f2bf(f0.z); o[3] = f2bf(f0.w);
    o[4] = f2bf(f1.x); o[5] = f2bf(f1.y); o[6] = f2bf(f1.z); o[7] = f2bf(f1.w);
    short8 s;
    __builtin_memcpy(&s, &o, 16);
    return s;
}

// ---------------------------------------------------------------------------
// K0: prep. blocks 0..255: w1sT 16-col transpose tiles; 256: WgT (144 cols:
// 128 W_gat^T + 8 fused attention-projection cols + 8 zero); 257: WsT;
// 258..513: states -> A_bf.
// ---------------------------------------------------------------------------
__global__ __launch_bounds__(256) void k0_prep(
    const float* __restrict__ w1s_W,     // [129][4096]
    const float* __restrict__ W_gat,     // [64][128]
    const float* __restrict__ att_a,     // [4][64]
    const float* __restrict__ states,    // [4096][128]
    const float* __restrict__ b1_W,      // [128][32]
    const float* __restrict__ wf_W,      // [128][32]
    const float* __restrict__ V1_W,      // [128][32]
    unsigned short* __restrict__ w1sT,   // [4096 cols][128 k] bf16
    unsigned short* __restrict__ WgT,    // [144 cols][64 k] bf16
    float* __restrict__ WsT,             // [96][128] fp32 (b1|wf|V1 transposed)
    unsigned short* __restrict__ A_bf)   // [4096][128] bf16
{
    __shared__ __align__(16) unsigned short T[128 * 72];  // 18KB, reused
    const int tid = threadIdx.x, bx = blockIdx.x;
    if (bx < 256) {
        const int c0 = bx * 16;
        const int cc = tid & 15, kr = tid >> 4;
        #pragma unroll
        for (int t = 0; t < 8; ++t) {
            int k = t * 16 + kr;
            T[cc * 136 + k] = f2bf(w1s_W[(size_t)k * 4096 + c0 + cc]);
        }
        __syncthreads();
        const int col = tid >> 4, seg = tid & 15;
        *(ushort8*)&w1sT[(size_t)(c0 + col) * 128 + seg * 8] =
            *(const ushort8*)&T[col * 136 + seg * 8];
    } else if (bx == 256) {
        #pragma unroll
        for (int t = 0; t < 32; ++t) {
            int i = t * 256 + tid;
            int k = i >> 7, c = i & 127;
            T[c * 72 + k] = f2bf(W_gat[k * 128 + c]);
        }
        __syncthreads();
        #pragma unroll
        for (int t = 0; t < 4; ++t) {
            int i = t * 256 + tid;
            int c = i >> 3, seg = i & 7;
            *(ushort8*)&WgT[c * 64 + seg * 8] = *(const ushort8*)&T[c * 72 + seg * 8];
        }
        // fused attention projections: cols 128+h = src-h, 132+h = dst-h
        {
            const int k = tid >> 2, h = tid & 3;
            float ss = 0.f, dd = 0.f;
            #pragma unroll
            for (int d = 0; d < 32; ++d) {
                float wv = W_gat[k * 128 + h * 32 + d];
                ss = fmaf(wv, att_a[h * 64 + d], ss);
                dd = fmaf(wv, att_a[h * 64 + 32 + d], dd);
            }
            WgT[(128 + h) * 64 + k] = f2bf(ss);
            WgT[(132 + h) * 64 + k] = f2bf(dd);
            WgT[(136 + h) * 64 + k] = 0;
            WgT[(140 + h) * 64 + k] = 0;
        }
    } else if (bx == 257) {
        for (int i = tid; i < 12288; i += 256) {
            int row = i >> 7, k = i & 127;
            int set = row >> 5, e = row & 31;
            const float* Wm = (set == 0) ? b1_W : ((set == 1) ? wf_W : V1_W);
            WsT[(size_t)row * 128 + k] = Wm[k * 32 + e];
        }
    } else {
        int u = (bx - 258) * 256 + tid;            // < 65536 units of 8 elems
        const float* src = states + (size_t)u * 8;
        float4 f0 = *(const float4*)src;
        float4 f1 = *(const float4*)(src + 4);
        short8 s = pack8(f0, f1);
        *(short8*)&A_bf[(size_t)u * 8] = s;
    }
}

// ---------------------------------------------------------------------------
// K1: GAT, wave-local (1 wave = 1 batch row), no LDS/barriers.
// MFMA1 over 9 tiles: tiles 0..7 = hp, tile 8 = fused src/dst projections
// (C-layout: col h = src-h, col 4+h = dst-h). Attention extraction is 8
// shuffles/head; softmax per-lane; MFMA2 (f16) aggregates g.
// ---------------------------------------------------------------------------
__global__ __launch_bounds__(256) void k1_gat(
    const float* __restrict__ hidden_states,  // [4096*16][64] fp32
    const unsigned short* __restrict__ WgT,   // [144][64] bf16
    const float* __restrict__ states,
    const float* __restrict__ WsT,            // [96][128] fp32
    const float* __restrict__ b1_b, const float* __restrict__ wf_b,
    const float* __restrict__ V1_b, const float* __restrict__ V2_W,
    const float* __restrict__ V2_b,
    unsigned short* __restrict__ g_bf,        // [B][4][16][32] bf16
    float* __restrict__ b1v, float* __restrict__ wfv, float* __restrict__ vv)
{
    const int b = blockIdx.x * 4 + (threadIdx.x >> 6);
    const int lane = threadIdx.x & 63, m = lane & 15, quad = lane >> 4;

    // ---- MFMA1: hp tiles + attention-projection tile ----
    const float* hrow = hidden_states + ((size_t)b * 16 + m) * 64;
    float4 f0 = *(const float4*)(hrow + quad * 8);
    float4 f1 = *(const float4*)(hrow + quad * 8 + 4);
    short8 a0 = pack8(f0, f1);
    f0 = *(const float4*)(hrow + 32 + quad * 8);
    f1 = *(const float4*)(hrow + 32 + quad * 8 + 4);
    short8 a1 = pack8(f0, f1);

    float4v hpt[9];
    #pragma unroll
    for (int nt = 0; nt < 9; ++nt) {
        const int c = nt * 16 + m;
        short8 bf0 = *(const short8*)&WgT[c * 64 + quad * 8];
        short8 bf1 = *(const short8*)&WgT[c * 64 + 32 + quad * 8];
        float4v z = (float4v){0.f, 0.f, 0.f, 0.f};
        z = __builtin_amdgcn_mfma_f32_16x16x32_bf16(a0, bf0, z, 0, 0, 0);
        z = __builtin_amdgcn_mfma_f32_16x16x32_bf16(a1, bf1, z, 0, 0, 0);
        hpt[nt] = z;
    }

    // ---- per head: attention + MFMA2 ----
    #pragma unroll
    for (int h = 0; h < 4; ++h) {
        // src[i=m]: reg (m&3) of lane ((m>>2)<<4 | h); dst[j=quad*4+jj]:
        // reg jj of lane (quad<<4 | (4+h))
        const int srcLane = ((m >> 2) << 4) | h;
        const int dstLane = (quad << 4) | (4 + h);
        float s0 = __shfl(hpt[8][0], srcLane), s1 = __shfl(hpt[8][1], srcLane);
        float s2 = __shfl(hpt[8][2], srcLane), s3 = __shfl(hpt[8][3], srcLane);
        const int sel = m & 3;
        float src_m = (sel == 0) ? s0 : (sel == 1) ? s1 : (sel == 2) ? s2 : s3;
        float pd[4];
        #pragma unroll
        for (int jj = 0; jj < 4; ++jj) pd[jj] = __shfl(hpt[8][jj], dstLane);

        // softmax over j for row i=m; this lane owns j = quad*4+jj
        float e_[4];
        #pragma unroll
        for (int jj = 0; jj < 4; ++jj) {
            float x = src_m + pd[jj];
            e_[jj] = fmaxf(x, 0.2f * x);       // leaky_relu(0.2)
        }
        float mx = fmaxf(fmaxf(e_[0], e_[1]), fmaxf(e_[2], e_[3]));
        mx = fmaxf(mx, __shfl_xor(mx, 16));
        mx = fmaxf(mx, __shfl_xor(mx, 32));
        float p_[4], ssum = 0.f;
        #pragma unroll
        for (int jj = 0; jj < 4; ++jj) { p_[jj] = __expf(e_[jj] - mx); ssum += p_[jj]; }
        ssum += __shfl_xor(ssum, 16);
        ssum += __shfl_xor(ssum, 32);
        const float inv = __builtin_amdgcn_rcpf(ssum);

        half4v bfrag;   // B[k=j=quad*4+jj][n=i=m] = attn[i][j]
        #pragma unroll
        for (int jj = 0; jj < 4; ++jj) bfrag[jj] = (_Float16)(p_[jj] * inv);

        #pragma unroll
        for (int p = 0; p < 2; ++p) {
            // A[m=d'][k=j=quad*4+t] = hp[quad*4+t][h*32+p*16+m] == hpt[2h+p]
            float4v ct = hpt[2 * h + p];
            half4v afrag;
            #pragma unroll
            for (int t = 0; t < 4; ++t) afrag[t] = (_Float16)ct[t];
            float4v z = (float4v){0.f, 0.f, 0.f, 0.f};
            z = __builtin_amdgcn_mfma_f32_16x16x16f16(afrag, bfrag, z, 0, 0, 0);
            // D: col = i = m, rows d' = quad*4+t -> g[i][p*16+quad*4+t]
            ushort4v o;
            #pragma unroll
            for (int t = 0; t < 4; ++t) {
                float x = z[t];
                float ex = __expf(x) - 1.f;    // elu
                x = (x > 0.f) ? x : ex;
                o[t] = f2bf(x);
            }
            *(ushort4v*)&g_bf[((size_t)b * 4 + h) * 512 + m * 32 + p * 16 + quad * 4] = o;
        }
    }

    // ---- small GEMVs vs WsT (k-contiguous): lane = (e=lane&31, khalf) ----
    const int e = lane & 31, khalf = lane >> 5;
    const float* srow = states + (size_t)b * 128 + khalf * 64;
    float accs[3];
    #pragma unroll
    for (int set = 0; set < 3; ++set) {
        const float* wrow = WsT + (size_t)(set * 32 + e) * 128 + khalf * 64;
        float a = 0.f;
        #pragma unroll
        for (int kk = 0; kk < 16; ++kk) {
            float4 wv = *(const float4*)(wrow + kk * 4);
            float4 sv = *(const float4*)(srow + kk * 4);
            a += wv.x * sv.x + wv.y * sv.y + wv.z * sv.z + wv.w * sv.w;
        }
        accs[set] = a + __shfl_xor(a, 32);
    }
    if (khalf == 0) {
        b1v[b * 32 + e] = accs[0] + b1_b[e];
        wfv[b * 32 + e] = fabsf(accs[1] + wf_b[e]);
    }
    float r3 = fmaxf(accs[2] + V1_b[e], 0.f) * V2_W[e];
    r3 += __shfl_xor(r3, 1);  r3 += __shfl_xor(r3, 2);
    r3 += __shfl_xor(r3, 4);  r3 += __shfl_xor(r3, 8);
    r3 += __shfl_xor(r3, 16);
    if (lane == 0) vv[b] = r3 + V2_b[0];
}

// ---------------------------------------------------------------------------
// K2_fused: per block = 16-row strip, 4 waves = 4 heads. Per wave, per
// e-group (16 e x 32 d = 512 cols): GEMM rows x cols via MFMA (K=128,
// A-frags register-resident, B-frags from global/L2) + uncertainty/bias
// fixup -> bf16 into a PRIVATE 16KB LDS tile (XOR-swizzled, bank-balanced),
// then 16 row-local MFMAs vs g + qs|.| + n-shuffle-reduce -> hid_part.
// No __syncthreads anywhere. w1state never touches HBM.
// ---------------------------------------------------------------------------
__global__ __launch_bounds__(256) void k2_fused(
    const unsigned short* __restrict__ A_bf,    // [4096][128]
    const unsigned short* __restrict__ w1sT,    // [4096 cols][128 k]
    const unsigned short* __restrict__ g_bf,    // [4096][4][16][32]
    const float* __restrict__ agent_qs,         // [4096][16]
    const float* __restrict__ uncertainty,      // [4096]
    const float* __restrict__ w1s_W,            // row 128 used
    const float* __restrict__ w1s_b,
    float* __restrict__ hid_part)               // [4][4096][32]
{
    const int r0 = blockIdx.x * 16;
    const int h = threadIdx.x >> 6;
    const int lane = threadIdx.x & 63, m = lane & 15, quad = lane >> 4;
    __shared__ __align__(16) unsigned short Wt[4][16 * 512];   // 64KB total
    unsigned short* Wtile = &Wt[h][0];

    // A-frags: rows r0..r0+15, reused across all 64 col-tiles
    short8 a[4];
    #pragma unroll
    for (int ks = 0; ks < 4; ++ks)
        a[ks] = *(const short8*)&A_bf[(size_t)(r0 + m) * 128 + ks * 32 + quad * 8];
    float us[4];
    #pragma unroll
    for (int reg = 0; reg < 4; ++reg)
        us[reg] = uncertainty[r0 + quad * 4 + reg];
    const float* w128 = w1s_W + (size_t)128 * 4096;

    #pragma unroll
    for (int eg = 0; eg < 2; ++eg) {
        const int cg0 = h * 1024 + eg * 512;

        // ---- GEMM: 16 rows x 512 cols, fixup, bf16 -> swizzled LDS ----
        #pragma unroll 4
        for (int tt = 0; tt < 32; ++tt) {
            const int cg = cg0 + tt * 16 + m;
            const float wfix = w128[cg], bias = w1s_b[cg];
            float4v acc = (float4v){0.f, 0.f, 0.f, 0.f};
            #pragma unroll
            for (int ks = 0; ks < 4; ++ks) {
                short8 bfr = *(const short8*)&w1sT[(size_t)cg * 128 + ks * 32 + quad * 8];
                acc = __builtin_amdgcn_mfma_f32_16x16x32_bf16(a[ks], bfr, acc, 0, 0, 0);
            }
            const int csw = (tt * 16 + m) ^ (quad << 4);   // row>>2 == quad
            #pragma unroll
            for (int reg = 0; reg < 4; ++reg)
                Wtile[(quad * 4 + reg) * 512 + csw] =
                    f2bf(acc[reg] + us[reg] * wfix + bias);
        }

        // ---- row-local contraction: Z[e,n] = sum_d W[e,d] g[n,d] ----
        #pragma unroll 2
        for (int r = 0; r < 16; ++r) {
            const int csw = (m * 32 + quad * 8) ^ ((r >> 2) << 4);
            short8 af = *(const short8*)&Wtile[r * 512 + csw];
            short8 gf = *(const short8*)&g_bf[((size_t)(r0 + r) * 4 + h) * 512 + m * 32 + quad * 8];
            const float qs_l = agent_qs[(r0 + r) * 16 + m];
            float4v z = (float4v){0.f, 0.f, 0.f, 0.f};
            z = __builtin_amdgcn_mfma_f32_16x16x32_bf16(af, gf, z, 0, 0, 0);
            float s[4];
            #pragma unroll
            for (int reg = 0; reg < 4; ++reg) s[reg] = fabsf(z[reg]) * qs_l;
            #pragma unroll
            for (int mask = 1; mask <= 8; mask <<= 1) {
                #pragma unroll
                for (int reg = 0; reg < 4; ++reg) s[reg] += __shfl_xor(s[reg], mask);
            }
            if (m == 0) {
                float4 o = {s[0], s[1], s[2], s[3]};
                *(float4*)&hid_part[((size_t)h * 4096 + r0 + r) * 32 + eg * 16 + quad * 4] = o;
            }
        }
    }
}

// ---------------------------------------------------------------------------
// K3: combine heads (mean/4), +b1, elu, *wf, reduce over e, +v -> out
// ---------------------------------------------------------------------------
__global__ __launch_bounds__(256) void k3_final(
    const float* __restrict__ hid_part,  // [4][4096][32]
    const float* __restrict__ b1v,
    const float* __restrict__ wfv,
    const float* __restrict__ vv,
    float* __restrict__ out)
{
    int idx = blockIdx.x * 256 + threadIdx.x;  // < 131072
    int row = idx >> 5, e = idx & 31;
    const size_t HS = (size_t)4096 * 32;
    size_t o = (size_t)row * 32 + e;
    float s = hid_part[o] + hid_part[HS + o] + hid_part[2 * HS + o] + hid_part[3 * HS + o];
    float hid = 0.25f * s + b1v[o];
    hid = (hid > 0.f) ? hid : expm1f(hid);
    float val = hid * wfv[o];
    #pragma unroll
    for (int off = 16; off > 0; off >>= 1) val += __shfl_down(val, off, 32);
    if ((threadIdx.x & 31) == 0) out[row] = val + vv[row];
}

// ---------------------------------------------------------------------------
extern "C" void kernel_launch(void* const* d_in, const int* in_sizes, int n_in,
                              void* d_out, int out_size, void* d_ws, size_t ws_size,
                              hipStream_t stream)
{
    const float* agent_qs      = (const float*)d_in[0];
    const float* states        = (const float*)d_in[1];
    const float* hidden_states = (const float*)d_in[2];
    const float* uncertainty   = (const float*)d_in[3];
    const float* W_gat         = (const float*)d_in[4];
    const float* att_a         = (const float*)d_in[5];
    const float* w1s_W         = (const float*)d_in[6];
    const float* w1s_b         = (const float*)d_in[7];
    const float* b1_W          = (const float*)d_in[8];
    const float* b1_b          = (const float*)d_in[9];
    const float* wf_W          = (const float*)d_in[10];
    const float* wf_b          = (const float*)d_in[11];
    const float* V1_W          = (const float*)d_in[12];
    const float* V1_b          = (const float*)d_in[13];
    const float* V2_W          = (const float*)d_in[14];
    const float* V2_b          = (const float*)d_in[15];

    char* w = (char*)d_ws;
    unsigned short* w1sT    = (unsigned short*)w;  w += (size_t)524288 * 2;
    unsigned short* WgT     = (unsigned short*)w;  w += (size_t)144 * 64 * 2;
    unsigned short* A_bf    = (unsigned short*)w;  w += (size_t)524288 * 2;
    float* WsT              = (float*)w;           w += (size_t)12288 * 4;
    unsigned short* g_bf    = (unsigned short*)w;  w += (size_t)8388608 * 2;
    float* hid_part         = (float*)w;           w += (size_t)4 * 4096 * 32 * 4;
    float* b1v              = (float*)w;           w += (size_t)131072 * 4;
    float* wfv              = (float*)w;           w += (size_t)131072 * 4;
    float* vv               = (float*)w;           w += (size_t)4096 * 4;
    float* out              = (float*)d_out;

    k0_prep<<<514, 256, 0, stream>>>(w1s_W, W_gat, att_a, states, b1_W, wf_W,
                                     V1_W, w1sT, WgT, WsT, A_bf);

    k1_gat<<<1024, 256, 0, stream>>>(hidden_states, WgT, states, WsT,
        b1_b, wf_b, V1_b, V2_W, V2_b, g_bf, b1v, wfv, vv);

    k2_fused<<<256, 256, 0, stream>>>(A_bf, w1sT, g_bf, agent_qs, uncertainty,
                                      w1s_W, w1s_b, hid_part);

    k3_final<<<512, 256, 0, stream>>>(hid_part, b1v, wfv, vv, out);
}

// Round 7
// 174.362 us; speedup vs baseline: 1.0980x; 1.0980x over previous
//
#include <hip/hip_runtime.h>
#include <math.h>

// N_AGENTS=16, RNN_H=64, N_HEADS=4, GAT_D=32, EMB=32, SDIM=128, B=4096 rows

typedef __attribute__((ext_vector_type(8))) short short8;
typedef __attribute__((ext_vector_type(8))) unsigned short ushort8;
typedef __attribute__((ext_vector_type(4))) unsigned short ushort4v;
typedef __attribute__((ext_vector_type(4))) float float4v;
typedef __attribute__((ext_vector_type(4))) _Float16 half4v;

static __device__ inline unsigned short f2bf(float f) {
    unsigned int x;
    __builtin_memcpy(&x, &f, 4);
    unsigned int r = x + 0x7fffu + ((x >> 16) & 1u);   // RNE
    return (unsigned short)(r >> 16);
}

static __device__ inline short8 pack8(float4 f0, float4 f1) {
    ushort8 o;
    o[0] = f2bf(f0.x); o[1] = f2bf(f0.y); o[2] = f2bf(f0.z); o[3] = f2bf(f0.w);
    o[4] = f2bf(f1.x); o[5] = f2bf(f1.y); o[6] = f2bf(f1.z); o[7] = f2bf(f1.w);
    short8 s;
    __builtin_memcpy(&s, &o, 16);
    return s;
}

// ---------------------------------------------------------------------------
// K0: prep. blocks 0..255: w1sT 16-col transpose tiles; 256: WgT (144 cols:
// 128 W_gat^T + 4 src-proj + 4 dst-proj + 8 zero); 257: WsT; 258..513:
// states -> A_bf.
// ---------------------------------------------------------------------------
__global__ __launch_bounds__(256) void k0_prep(
    const float* __restrict__ w1s_W,     // [129][4096]
    const float* __restrict__ W_gat,     // [64][128]
    const float* __restrict__ att_a,     // [4][64]
    const float* __restrict__ states,    // [4096][128]
    const float* __restrict__ b1_W,      // [128][32]
    const float* __restrict__ wf_W,      // [128][32]
    const float* __restrict__ V1_W,      // [128][32]
    unsigned short* __restrict__ w1sT,   // [4096 cols][128 k] bf16
    unsigned short* __restrict__ WgT,    // [144 cols][64 k] bf16
    float* __restrict__ WsT,             // [96][128] fp32 (b1|wf|V1 transposed)
    unsigned short* __restrict__ A_bf)   // [4096][128] bf16
{
    __shared__ __align__(16) unsigned short T[128 * 72];  // 18KB, reused
    const int tid = threadIdx.x, bx = blockIdx.x;
    if (bx < 256) {
        const int c0 = bx * 16;
        const int cc = tid & 15, kr = tid >> 4;
        #pragma unroll
        for (int t = 0; t < 8; ++t) {
            int k = t * 16 + kr;
            T[cc * 136 + k] = f2bf(w1s_W[(size_t)k * 4096 + c0 + cc]);
        }
        __syncthreads();
        const int col = tid >> 4, seg = tid & 15;
        *(ushort8*)&w1sT[(size_t)(c0 + col) * 128 + seg * 8] =
            *(const ushort8*)&T[col * 136 + seg * 8];
    } else if (bx == 256) {
        #pragma unroll
        for (int t = 0; t < 32; ++t) {
            int i = t * 256 + tid;
            int k = i >> 7, c = i & 127;
            T[c * 72 + k] = f2bf(W_gat[k * 128 + c]);
        }
        __syncthreads();
        #pragma unroll
        for (int t = 0; t < 4; ++t) {
            int i = t * 256 + tid;
            int c = i >> 3, seg = i & 7;
            *(ushort8*)&WgT[c * 64 + seg * 8] = *(const ushort8*)&T[c * 72 + seg * 8];
        }
        // fused attention projections: cols 128+h = src-h, 132+h = dst-h
        {
            const int k = tid >> 2, h = tid & 3;
            float ss = 0.f, dd = 0.f;
            #pragma unroll
            for (int d = 0; d < 32; ++d) {
                float wv = W_gat[k * 128 + h * 32 + d];
                ss = fmaf(wv, att_a[h * 64 + d], ss);
                dd = fmaf(wv, att_a[h * 64 + 32 + d], dd);
            }
            WgT[(128 + h) * 64 + k] = f2bf(ss);
            WgT[(132 + h) * 64 + k] = f2bf(dd);
            WgT[(136 + h) * 64 + k] = 0;
            WgT[(140 + h) * 64 + k] = 0;
        }
    } else if (bx == 257) {
        for (int i = tid; i < 12288; i += 256) {
            int row = i >> 7, k = i & 127;
            int set = row >> 5, e = row & 31;
            const float* Wm = (set == 0) ? b1_W : ((set == 1) ? wf_W : V1_W);
            WsT[(size_t)row * 128 + k] = Wm[k * 32 + e];
        }
    } else {
        int u = (bx - 258) * 256 + tid;            // < 65536 units of 8 elems
        const float* src = states + (size_t)u * 8;
        float4 f0 = *(const float4*)src;
        float4 f1 = *(const float4*)(src + 4);
        short8 s = pack8(f0, f1);
        *(short8*)&A_bf[(size_t)u * 8] = s;
    }
}

// ---------------------------------------------------------------------------
// K1: GAT, 1 wave = 1 batch row. MFMA1 over 9 tiles (hp + fused src/dst
// projections). Attention routing via 1.3KB per-wave LDS scratch:
// 1 ds_write_b128 + per head (1 ds_read_b32 + 1 ds_read_b128) — replaces
// the serial bpermute chains. MFMA2 (f16) aggregates g. Then small GEMVs.
// ---------------------------------------------------------------------------
__global__ __launch_bounds__(256) void k1_gat(
    const float* __restrict__ hidden_states,  // [4096*16][64] fp32
    const unsigned short* __restrict__ WgT,   // [144][64] bf16
    const float* __restrict__ states,
    const float* __restrict__ WsT,            // [96][128] fp32
    const float* __restrict__ b1_b, const float* __restrict__ wf_b,
    const float* __restrict__ V1_b, const float* __restrict__ V2_W,
    const float* __restrict__ V2_b,
    unsigned short* __restrict__ g_bf,        // [B][4][16][32] bf16
    float* __restrict__ b1v, float* __restrict__ wfv, float* __restrict__ vv)
{
    const int b = blockIdx.x * 4 + (threadIdx.x >> 6);
    const int lane = threadIdx.x & 63, m = lane & 15, quad = lane >> 4;
    __shared__ __align__(16) float sc[4 * 320];   // per-wave scratch, 5KB
    float* scr = &sc[(threadIdx.x >> 6) * 320];

    // ---- MFMA1: hp tiles + attention-projection tile ----
    const float* hrow = hidden_states + ((size_t)b * 16 + m) * 64;
    float4 f0 = *(const float4*)(hrow + quad * 8);
    float4 f1 = *(const float4*)(hrow + quad * 8 + 4);
    short8 a0 = pack8(f0, f1);
    f0 = *(const float4*)(hrow + 32 + quad * 8);
    f1 = *(const float4*)(hrow + 32 + quad * 8 + 4);
    short8 a1 = pack8(f0, f1);

    float4v hpt[9];
    #pragma unroll
    for (int nt = 0; nt < 9; ++nt) {
        const int c = nt * 16 + m;
        short8 bf0 = *(const short8*)&WgT[c * 64 + quad * 8];
        short8 bf1 = *(const short8*)&WgT[c * 64 + 32 + quad * 8];
        float4v z = (float4v){0.f, 0.f, 0.f, 0.f};
        z = __builtin_amdgcn_mfma_f32_16x16x32_bf16(a0, bf0, z, 0, 0, 0);
        z = __builtin_amdgcn_mfma_f32_16x16x32_bf16(a1, bf1, z, 0, 0, 0);
        hpt[nt] = z;
    }

    // stash projection tile (C-layout: [row=agent][col<8]) transposed into
    // scratch[col*20 + row] (stride 20: b128-aligned, bank-spread)
    {
        float4 pr = {hpt[8][0], hpt[8][1], hpt[8][2], hpt[8][3]};
        *(float4*)&scr[m * 20 + quad * 4] = pr;
    }

    // ---- per head: attention + MFMA2 ----
    #pragma unroll
    for (int h = 0; h < 4; ++h) {
        const float src_m = scr[h * 20 + m];                       // src-h[i=m]
        float4 pdv = *(const float4*)&scr[(4 + h) * 20 + quad * 4];// dst-h[j]
        float pd[4] = {pdv.x, pdv.y, pdv.z, pdv.w};

        // softmax over j for row i=m; this lane owns j = quad*4+jj
        float e_[4];
        #pragma unroll
        for (int jj = 0; jj < 4; ++jj) {
            float x = src_m + pd[jj];
            e_[jj] = fmaxf(x, 0.2f * x);       // leaky_relu(0.2)
        }
        float mx = fmaxf(fmaxf(e_[0], e_[1]), fmaxf(e_[2], e_[3]));
        mx = fmaxf(mx, __shfl_xor(mx, 16));
        mx = fmaxf(mx, __shfl_xor(mx, 32));
        float p_[4], ssum = 0.f;
        #pragma unroll
        for (int jj = 0; jj < 4; ++jj) { p_[jj] = __expf(e_[jj] - mx); ssum += p_[jj]; }
        ssum += __shfl_xor(ssum, 16);
        ssum += __shfl_xor(ssum, 32);
        const float inv = __builtin_amdgcn_rcpf(ssum);

        half4v bfrag;   // B[k=j=quad*4+jj][n=i=m] = attn[i][j]
        #pragma unroll
        for (int jj = 0; jj < 4; ++jj) bfrag[jj] = (_Float16)(p_[jj] * inv);

        #pragma unroll
        for (int p = 0; p < 2; ++p) {
            // A[m=d'][k=j=quad*4+t] = hp[quad*4+t][h*32+p*16+m] == hpt[2h+p]
            float4v ct = hpt[2 * h + p];
            half4v afrag;
            #pragma unroll
            for (int t = 0; t < 4; ++t) afrag[t] = (_Float16)ct[t];
            float4v z = (float4v){0.f, 0.f, 0.f, 0.f};
            z = __builtin_amdgcn_mfma_f32_16x16x16f16(afrag, bfrag, z, 0, 0, 0);
            // D: col = i = m, rows d' = quad*4+t -> g[i][p*16+quad*4+t]
            ushort4v o;
            #pragma unroll
            for (int t = 0; t < 4; ++t) {
                float x = z[t];
                float ex = __expf(x) - 1.f;    // elu
                x = (x > 0.f) ? x : ex;
                o[t] = f2bf(x);
            }
            *(ushort4v*)&g_bf[((size_t)b * 4 + h) * 512 + m * 32 + p * 16 + quad * 4] = o;
        }
    }

    // ---- small GEMVs vs WsT (k-contiguous): lane = (e=lane&31, khalf) ----
    const int e = lane & 31, khalf = lane >> 5;
    const float* srow = states + (size_t)b * 128 + khalf * 64;
    float accs[3];
    #pragma unroll
    for (int set = 0; set < 3; ++set) {
        const float* wrow = WsT + (size_t)(set * 32 + e) * 128 + khalf * 64;
        float a = 0.f;
        #pragma unroll
        for (int kk = 0; kk < 16; ++kk) {
            float4 wv = *(const float4*)(wrow + kk * 4);
            float4 sv = *(const float4*)(srow + kk * 4);
            a += wv.x * sv.x + wv.y * sv.y + wv.z * sv.z + wv.w * sv.w;
        }
        accs[set] = a + __shfl_xor(a, 32);
    }
    if (khalf == 0) {
        b1v[b * 32 + e] = accs[0] + b1_b[e];
        wfv[b * 32 + e] = fabsf(accs[1] + wf_b[e]);
    }
    float r3 = fmaxf(accs[2] + V1_b[e], 0.f) * V2_W[e];
    r3 += __shfl_xor(r3, 1);  r3 += __shfl_xor(r3, 2);
    r3 += __shfl_xor(r3, 4);  r3 += __shfl_xor(r3, 8);
    r3 += __shfl_xor(r3, 16);
    if (lane == 0) vv[b] = r3 + V2_b[0];
}

// ---------------------------------------------------------------------------
// K2_mix: fused GEMM + contraction, occupancy-first.
// Block = (32-row strip, head h, e-group eg of 8 e's = 256 cols); grid
// 128x4x4 = 2048 blocks x 4 waves. Phase 1: each wave GEMMs 64 cols
// (A-frags register-resident, B from L2), fixup -> fp32 LDS tile (37KB,
// bank-padded). One barrier. Phase 2: 8 rows/wave, 1 contraction MFMA each
// (A from LDS, B=g from global), qs|.|, n-shuffle-reduce -> hid_part.
// ---------------------------------------------------------------------------
__global__ __launch_bounds__(256) void k2_mix(
    const unsigned short* __restrict__ A_bf,    // [4096][128]
    const unsigned short* __restrict__ w1sT,    // [4096 cols][128 k]
    const unsigned short* __restrict__ g_bf,    // [4096][4][16][32]
    const float* __restrict__ agent_qs,         // [4096][16]
    const float* __restrict__ uncertainty,      // [4096]
    const float* __restrict__ w1s_W,            // row 128 used
    const float* __restrict__ w1s_b,
    float* __restrict__ hid_part)               // [4][4096][32]
{
    const int r0 = blockIdx.x * 32;
    const int h  = blockIdx.y;
    const int eg = blockIdx.z;
    const int wave = threadIdx.x >> 6;
    const int lane = threadIdx.x & 63, m = lane & 15, quad = lane >> 4;
    __shared__ __align__(16) float Wt[32 * 292];   // [row][e_loc*36 + d]

    // A-frags: rows r0..r0+31 (2 m-tiles), register-resident
    short8 a[2][4];
    #pragma unroll
    for (int mt = 0; mt < 2; ++mt)
        #pragma unroll
        for (int ks = 0; ks < 4; ++ks)
            a[mt][ks] = *(const short8*)&A_bf[(size_t)(r0 + mt * 16 + m) * 128 + ks * 32 + quad * 8];
    float us[2][4];
    #pragma unroll
    for (int mt = 0; mt < 2; ++mt)
        #pragma unroll
        for (int reg = 0; reg < 4; ++reg)
            us[mt][reg] = uncertainty[r0 + mt * 16 + quad * 4 + reg];

    const float* w128 = w1s_W + (size_t)128 * 4096;
    const int cbase = h * 1024 + eg * 256;

    // ---- Phase 1: GEMM 32 rows x 256 cols; wave w -> col-tiles w*4..+4 ----
    #pragma unroll
    for (int t = 0; t < 4; ++t) {
        const int ct = wave * 4 + t;
        const int c_loc = ct * 16 + m;
        const int cg = cbase + c_loc;
        const float wfix = w128[cg], bias = w1s_b[cg];
        float4v acc0 = (float4v){0.f, 0.f, 0.f, 0.f};
        float4v acc1 = (float4v){0.f, 0.f, 0.f, 0.f};
        #pragma unroll
        for (int ks = 0; ks < 4; ++ks) {
            short8 bfr = *(const short8*)&w1sT[(size_t)cg * 128 + ks * 32 + quad * 8];
            acc0 = __builtin_amdgcn_mfma_f32_16x16x32_bf16(a[0][ks], bfr, acc0, 0, 0, 0);
            acc1 = __builtin_amdgcn_mfma_f32_16x16x32_bf16(a[1][ks], bfr, acc1, 0, 0, 0);
        }
        const int el = c_loc >> 5, d = c_loc & 31;
        #pragma unroll
        for (int reg = 0; reg < 4; ++reg) {
            Wt[(quad * 4 + reg) * 292 + el * 36 + d]        = acc0[reg] + us[0][reg] * wfix + bias;
            Wt[(16 + quad * 4 + reg) * 292 + el * 36 + d]   = acc1[reg] + us[1][reg] * wfix + bias;
        }
    }
    __syncthreads();

    // ---- Phase 2: contraction; wave w -> rows w*8..+8 ----
    #pragma unroll
    for (int rr = 0; rr < 8; ++rr) {
        const int r = wave * 8 + rr;
        const float* wrow = &Wt[r * 292 + (m & 7) * 36 + quad * 8];
        float4 w0 = *(const float4*)wrow;
        float4 w1 = *(const float4*)(wrow + 4);
        short8 af = pack8(w0, w1);                  // A[e' = m&7][d]
        short8 gf = *(const short8*)&g_bf[((size_t)(r0 + r) * 4 + h) * 512 + m * 32 + quad * 8];
        const float qs_l = agent_qs[(r0 + r) * 16 + m];
        float4v z = (float4v){0.f, 0.f, 0.f, 0.f};
        z = __builtin_amdgcn_mfma_f32_16x16x32_bf16(af, gf, z, 0, 0, 0);
        float s[4];
        #pragma unroll
        for (int reg = 0; reg < 4; ++reg) s[reg] = fabsf(z[reg]) * qs_l;
        #pragma unroll
        for (int mask = 1; mask <= 8; mask <<= 1) {
            #pragma unroll
            for (int reg = 0; reg < 4; ++reg) s[reg] += __shfl_xor(s[reg], mask);
        }
        if (m == 0 && quad < 2) {   // e = quad*4+reg valid for e<8
            float4 o = {s[0], s[1], s[2], s[3]};
            *(float4*)&hid_part[((size_t)h * 4096 + r0 + r) * 32 + eg * 8 + quad * 4] = o;
        }
    }
}

// ---------------------------------------------------------------------------
// K3: combine heads (mean/4), +b1, elu, *wf, reduce over e, +v -> out
// ---------------------------------------------------------------------------
__global__ __launch_bounds__(256) void k3_final(
    const float* __restrict__ hid_part,  // [4][4096][32]
    const float* __restrict__ b1v,
    const float* __restrict__ wfv,
    const float* __restrict__ vv,
    float* __restrict__ out)
{
    int idx = blockIdx.x * 256 + threadIdx.x;  // < 131072
    int row = idx >> 5, e = idx & 31;
    const size_t HS = (size_t)4096 * 32;
    size_t o = (size_t)row * 32 + e;
    float s = hid_part[o] + hid_part[HS + o] + hid_part[2 * HS + o] + hid_part[3 * HS + o];
    float hid = 0.25f * s + b1v[o];
    hid = (hid > 0.f) ? hid : expm1f(hid);
    float val = hid * wfv[o];
    #pragma unroll
    for (int off = 16; off > 0; off >>= 1) val += __shfl_down(val, off, 32);
    if ((threadIdx.x & 31) == 0) out[row] = val + vv[row];
}

// ---------------------------------------------------------------------------
extern "C" void kernel_launch(void* const* d_in, const int* in_sizes, int n_in,
                              void* d_out, int out_size, void* d_ws, size_t ws_size,
                              hipStream_t stream)
{
    const float* agent_qs      = (const float*)d_in[0];
    const float* states        = (const float*)d_in[1];
    const float* hidden_states = (const float*)d_in[2];
    const float* uncertainty   = (const float*)d_in[3];
    const float* W_gat         = (const float*)d_in[4];
    const float* att_a         = (const float*)d_in[5];
    const float* w1s_W         = (const float*)d_in[6];
    const float* w1s_b         = (const float*)d_in[7];
    const float* b1_W          = (const float*)d_in[8];
    const float* b1_b          = (const float*)d_in[9];
    const float* wf_W          = (const float*)d_in[10];
    const float* wf_b          = (const float*)d_in[11];
    const float* V1_W          = (const float*)d_in[12];
    const float* V1_b          = (const float*)d_in[13];
    const float* V2_W          = (const float*)d_in[14];
    const float* V2_b          = (const float*)d_in[15];

    char* w = (char*)d_ws;
    unsigned short* w1sT    = (unsigned short*)w;  w += (size_t)524288 * 2;
    unsigned short* WgT     = (unsigned short*)w;  w += (size_t)144 * 64 * 2;
    unsigned short* A_bf    = (unsigned short*)w;  w += (size_t)524288 * 2;
    float* WsT              = (float*)w;           w += (size_t)12288 * 4;
    unsigned short* g_bf    = (unsigned short*)w;  w += (size_t)8388608 * 2;
    float* hid_part         = (float*)w;           w += (size_t)4 * 4096 * 32 * 4;
    float* b1v              = (float*)w;           w += (size_t)131072 * 4;
    float* wfv              = (float*)w;           w += (size_t)131072 * 4;
    float* vv               = (float*)w;           w += (size_t)4096 * 4;
    float* out              = (float*)d_out;

    k0_prep<<<514, 256, 0, stream>>>(w1s_W, W_gat, att_a, states, b1_W, wf_W,
                                     V1_W, w1sT, WgT, WsT, A_bf);

    k1_gat<<<1024, 256, 0, stream>>>(hidden_states, WgT, states, WsT,
        b1_b, wf_b, V1_b, V2_W, V2_b, g_bf, b1v, wfv, vv);

    dim3 gmix(128, 4, 4);
    k2_mix<<<gmix, 256, 0, stream>>>(A_bf, w1sT, g_bf, agent_qs, uncertainty,
                                     w1s_W, w1s_b, hid_part);

    k3_final<<<512, 256, 0, stream>>>(hid_part, b1v, wfv, vv, out);
}